// Round 11
// baseline (119.016 us; speedup 1.0000x reference)
//
#include <hip/hip_runtime.h>
#include <math.h>

// SocialPooling: B=8, N=8192, D=64.
// w_ij = exp(-d2/50) if sqrt(max(d2,1e-12)) <= 10 else 0;
// keep w >= (32nd largest w in row); normalize by clip(row_sum,1e-8);
// out[b,i,d] = sum_j w_ij * F[b,j,d].
//
// R11: ATTRIBUTION ROUND. Kernels byte-identical to passing R10; the only
// change is k_select is launched 4x (idempotent: same inputs -> rewrites
// identical kv/kn; deterministic). rocprof top-5 is saturated by 44-45us
// harness poison fills, so per-kernel durations are invisible; the total
// delta vs R10 (69.7us) yields select's duration: s = (T11 - 69.7 - ~2)/3.
//   H_select (s~35-40): T11 ~ 175-190  -> R12 attacks selection, re-fused.
//   H_pool   (s~8-15):  T11 ~  95-117  -> R12 attacks gather BW/occupancy.

constexpr int   NCELL  = 10;
constexpr int   NCELL2 = 100;
constexpr int   MAXC   = 416;   // candidates/row: lambda~257, std~16 (+10σ)
constexpr int   MAXK   = 64;    // kept: 32 + boundary ties
constexpr float BUCKSC = 2.56f; // d2 in [0,100] -> bucket 0..255 (monotone)
constexpr int   NXCD   = 8;

__device__ __forceinline__ int cell_x(float x) {
    int c = (int)(x * 0.09765625f);   // 1/10.24 exact in f32
    return min(max(c, 0), NCELL - 1);
}
__device__ __forceinline__ int cell_of(float2 c) {
    return cell_x(c.y) * NCELL + cell_x(c.x);
}

// wave-synchronous LDS handoff (LDS is wave-private: drain lgkmcnt only)
__device__ __forceinline__ void wsync() {
    __builtin_amdgcn_wave_barrier();
    asm volatile("s_waitcnt lgkmcnt(0)" ::: "memory");
    __builtin_amdgcn_wave_barrier();
}

// ---- fused prep: zero + count + parallel scan + scatter, one block ----
__global__ __launch_bounds__(1024)
void k_prep(const float* __restrict__ C, int* __restrict__ cellStart,
            float2* __restrict__ bXY, int* __restrict__ bIdx, int N)
{
    __shared__ int h[128];
    __shared__ int cur[NCELL2];
    const int t = threadIdx.x;
    if (t < 128) h[t] = 0;
    __syncthreads();
    const float2* C2 = (const float2*)C;
    for (int j = t; j < N; j += 1024) atomicAdd(&h[cell_of(C2[j])], 1);
    __syncthreads();
    #pragma unroll
    for (int o = 1; o < 128; o <<= 1) {
        int u = (t < 128 && t >= o) ? h[t - o] : 0;
        __syncthreads();
        if (t < 128) h[t] += u;
        __syncthreads();
    }
    if (t < NCELL2) {
        int s = (t == 0) ? 0 : h[t - 1];
        cur[t] = s; cellStart[t] = s;
        if (t == 0) cellStart[NCELL2] = h[NCELL2 - 1];
    }
    __syncthreads();
    for (int j = t; j < N; j += 1024) {
        float2 c = C2[j];
        int pos = atomicAdd(&cur[cell_of(c)], 1);
        bXY[pos] = c; bIdx[pos] = j;
    }
}

// ---- batch-interleaved binned copy: FB2[p][b][d] = F[b][bIdx[p]][d] ----
__global__ __launch_bounds__(256)
void k_permute(const float* __restrict__ F, const int* __restrict__ bIdx,
               float* __restrict__ FB2)
{
    const int t  = blockIdx.x * 256 + threadIdx.x;
    const int p  = t >> 7;
    const int r  = t & 127;
    const int b  = r >> 4;
    const int dq = r & 15;
    const int j  = bIdx[p];
    const float4 v = ((const float4*)(F + ((size_t)b * 8192 + (size_t)j) * 64))[dq];
    ((float4*)(FB2 + (size_t)p * 512 + b * 64))[dq] = v;
}

// ---- selection: passes 1-3 (bit-identical to R9) + write (w,p) lists ----
__global__ __launch_bounds__(256, 8)
void k_select(const float2* __restrict__ bXY,
              const int* __restrict__ bIdx,
              const int* __restrict__ cellStart,
              float2* __restrict__ kv,       // [N][MAXK] (w, bitcast p)
              int2* __restrict__ kn,         // [N] (Kpad, original i)
              int N)
{
    __shared__ float  s_cd2[4][MAXC];
    __shared__ int    s_cjj[4][MAXC];
    __shared__ __align__(16) int s_hist[4][256];
    __shared__ float  s_blist[4][32];
    __shared__ float2 s_kwj[4][MAXK];

    const int t = threadIdx.x, wid = t >> 6, lane = t & 63;
    float*  cd2   = s_cd2[wid];
    int*    cjj   = s_cjj[wid];
    int*    hist  = s_hist[wid];
    float*  blist = s_blist[wid];
    float2* kwj   = s_kwj[wid];

    *(int4*)&hist[lane * 4] = make_int4(0, 0, 0, 0);

    const int bid = blockIdx.x, nb = gridDim.x;
    const int sb = (nb % NXCD == 0) ? (bid % NXCD) * (nb / NXCD) + bid / NXCD : bid;
    const int q = sb * 4 + wid;
    if (q >= N) return;

    const float2 ci = bXY[q];
    const int    i  = bIdx[q];
    const int cx = cell_x(ci.x), cy = cell_x(ci.y);
    const unsigned long long below = (1ull << lane) - 1ull;

    // pass 1: scan 3x3 cells; ballot+popc compaction; store position p
    int mc = 0;
    for (int ry = max(cy - 1, 0); ry <= min(cy + 1, NCELL - 1); ++ry) {
        const int c0 = ry * NCELL + max(cx - 1, 0);
        const int c1 = ry * NCELL + min(cx + 1, NCELL - 1);
        const int s = cellStart[c0], e = cellStart[c1 + 1];
        for (int p0 = s; p0 < e; p0 += 64) {
            const int p = p0 + lane;
            bool hit = false; float d2 = 0.0f;
            if (p < e) {
                float2 cp = bXY[p];
                float dx = ci.x - cp.x, dy = ci.y - cp.y;
                d2 = dx * dx + dy * dy;
                float d = sqrtf(fmaxf(d2, 1e-12f));   // exact ref boundary
                hit = (d <= 10.0f);
            }
            unsigned long long mk = __ballot(hit);
            int off = __popcll(mk & below);
            if (hit && mc + off < MAXC) { cd2[mc + off] = d2; cjj[mc + off] = p; }
            mc += (int)__popcll(mk);
        }
    }
    wsync();
    const int M = min(mc, MAXC);

    // pass 2: 32nd-smallest d2 via per-wave 256-bin histogram
    float thr_d2, thr_w;
    if (M > 32) {
        for (int k = lane; k < M; k += 64)
            atomicAdd(&hist[min(255, (int)(cd2[k] * BUCKSC))], 1);
        wsync();
        int4 h4 = *(const int4*)&hist[lane * 4];
        int hh0 = h4.x, hh1 = h4.y, hh2 = h4.z, hh3 = h4.w;
        int tot = hh0 + hh1 + hh2 + hh3;
        int sc = tot;
        #pragma unroll
        for (int o = 1; o < 64; o <<= 1) {
            int v = __shfl_up(sc, o);
            if (lane >= o) sc += v;
        }
        int ce = sc - tot;
        int fb = -1, fce = 0;
        if (ce <= 31 && 31 < ce + hh0) { fb = lane * 4 + 0; fce = ce; } ce += hh0;
        if (fb < 0 && ce <= 31 && 31 < ce + hh1) { fb = lane * 4 + 1; fce = ce; } ce += hh1;
        if (fb < 0 && ce <= 31 && 31 < ce + hh2) { fb = lane * 4 + 2; fce = ce; } ce += hh2;
        if (fb < 0 && ce <= 31 && 31 < ce + hh3) { fb = lane * 4 + 3; fce = ce; }
        unsigned long long mk1 = __ballot(fb >= 0);
        int src1 = (mk1 != 0ull) ? (__ffsll((unsigned long long)mk1) - 1) : 0;
        const int bstar   = __shfl(fb,  src1);
        const int cumexcl = __shfl(fce, src1);
        int bn = 0;
        for (int k0 = 0; k0 < M; k0 += 64) {
            const int k = k0 + lane;
            bool inb = (k < M) && (min(255, (int)(cd2[k] * BUCKSC)) == bstar);
            unsigned long long mk = __ballot(inb);
            int off = __popcll(mk & below);
            if (inb && bn + off < 32) blist[bn + off] = cd2[k];
            bn += (int)__popcll(mk);
        }
        wsync();
        bn = min(bn, 32);
        float mine = 0.0f; int ok = 0;
        if (lane < bn) {
            mine = blist[lane];
            int cl = 0, ceq = 0;
            for (int m = 0; m < bn; ++m) {
                cl  += (blist[m] <  mine);
                ceq += (blist[m] == mine);
            }
            int r = cumexcl + cl;
            ok = (r <= 31 && 31 < r + ceq);
        }
        unsigned long long mk2 = __ballot(ok);
        int src2 = (mk2 != 0ull) ? (__ffsll((unsigned long long)mk2) - 1) : 0;
        thr_d2 = __shfl(mine, src2);
        thr_w  = expf(-(thr_d2 / 50.0f));
    } else {
        thr_d2 = 3.4e38f;
        thr_w  = 0.0f;
    }

    // pass 3: keep w >= thr_w over d2-margin superset (tie-exact); store p
    const float marg = thr_d2 + 1e-4f;
    int kc = 0;
    for (int k0 = 0; k0 < M; k0 += 64) {
        const int k = k0 + lane;
        bool keep = false; float w = 0.0f; int jj = 0;
        if (k < M && cd2[k] <= marg) {
            w = expf(-(cd2[k] / 50.0f));
            if (w >= thr_w) { keep = true; jj = cjj[k]; }
        }
        unsigned long long mk = __ballot(keep);
        int off = __popcll(mk & below);
        if (keep && kc + off < MAXK)
            kwj[kc + off] = make_float2(w, __int_as_float(jj));
        kc += (int)__popcll(mk);
    }
    wsync();
    const int K = min(kc, MAXK);

    // normalize in registers; lane l holds pair l
    float2 pr = make_float2(0.0f, 0.0f);
    if (lane < K) pr = kwj[lane];
    float v = pr.x;
    #pragma unroll
    for (int o = 32; o > 0; o >>= 1) v += __shfl_xor(v, o);
    const float ssum = fmaxf(v, 1e-8f);
    const float wn = pr.x / ssum;

    kv[(size_t)q * MAXK + lane] =
        (lane < K) ? make_float2(wn, pr.y) : make_float2(0.0f, __int_as_float(0));
    if (lane == 0) kn[q] = make_int2((K + 3) & ~3, i);
}

// ---- pooling: 512 blocks x 4 waves x 4 sequential row-phases ----
__global__ __launch_bounds__(256)
void k_pool(const float* __restrict__ FB2,
            const float2* __restrict__ kv,
            const int2* __restrict__ kn,
            float* __restrict__ out)
{
    const int wid = threadIdx.x >> 6, lane = threadIdx.x & 63;
    const int c = blockIdx.x & 7;
    const int l = blockIdx.x >> 3;         // [0,64)
    const int b  = lane >> 3;              // batch
    const int d8 = (lane & 7) * 8;         // 8 dims
    const size_t NL = (size_t)8192 * 64;

    for (int ph = 0; ph < 4; ++ph) {
        const int row = c * 1024 + ph * 256 + l * 4 + wid;
        const int2 kni = kn[row];
        const int Kp = kni.x;
        const int i  = kni.y;
        const float2 prl = kv[(size_t)row * MAXK + lane];
        const int wi = __float_as_int(prl.x);
        const int pi = __float_as_int(prl.y);
        float4 a0 = make_float4(0.f, 0.f, 0.f, 0.f);
        float4 a1 = make_float4(0.f, 0.f, 0.f, 0.f);
        for (int k = 0; k < Kp; k += 4) {
            #pragma unroll
            for (int u = 0; u < 4; ++u) {
                const float w = __int_as_float(__builtin_amdgcn_readlane(wi, k + u));
                const int   p = __builtin_amdgcn_readlane(pi, k + u);
                const float* s = FB2 + (size_t)p * 512 + b * 64 + d8;
                float4 f0 = *(const float4*)s;
                float4 f1 = *(const float4*)(s + 4);
                a0.x += w * f0.x; a0.y += w * f0.y; a0.z += w * f0.z; a0.w += w * f0.w;
                a1.x += w * f1.x; a1.y += w * f1.y; a1.z += w * f1.z; a1.w += w * f1.w;
            }
        }
        float* O = out + (size_t)b * NL + (size_t)i * 64 + d8;
        *(float4*)O = a0;
        *(float4*)(O + 4) = a1;
    }
}

// ---- generic fallback (R9's fused kernel, original-F gather) ----
__global__ __launch_bounds__(256, 8)
void social_pool_fused(const float* __restrict__ F,
                       const float2* __restrict__ bXY,
                       const int* __restrict__ bIdx,
                       const int* __restrict__ cellStart,
                       float* __restrict__ out, int N, int B)
{
    __shared__ float  s_cd2[4][MAXC];
    __shared__ int    s_cjj[4][MAXC];
    __shared__ __align__(16) int s_hist[4][256];
    __shared__ float  s_blist[4][32];
    __shared__ float2 s_kwj[4][MAXK];

    const int t = threadIdx.x, wid = t >> 6, lane = t & 63;
    float*  cd2   = s_cd2[wid];
    int*    cjj   = s_cjj[wid];
    int*    hist  = s_hist[wid];
    float*  blist = s_blist[wid];
    float2* kwj   = s_kwj[wid];

    *(int4*)&hist[lane * 4] = make_int4(0, 0, 0, 0);

    const int bid = blockIdx.x, nb = gridDim.x;
    const int sb = (nb % NXCD == 0) ? (bid % NXCD) * (nb / NXCD) + bid / NXCD : bid;
    const int q = sb * 4 + wid;
    if (q >= N) return;

    const float2 ci = bXY[q];
    const int    i  = bIdx[q];
    const int cx = cell_x(ci.x), cy = cell_x(ci.y);
    const unsigned long long below = (1ull << lane) - 1ull;

    int mc = 0;
    for (int ry = max(cy - 1, 0); ry <= min(cy + 1, NCELL - 1); ++ry) {
        const int c0 = ry * NCELL + max(cx - 1, 0);
        const int c1 = ry * NCELL + min(cx + 1, NCELL - 1);
        const int s = cellStart[c0], e = cellStart[c1 + 1];
        for (int p0 = s; p0 < e; p0 += 64) {
            const int p = p0 + lane;
            bool hit = false; float d2 = 0.0f;
            if (p < e) {
                float2 cp = bXY[p];
                float dx = ci.x - cp.x, dy = ci.y - cp.y;
                d2 = dx * dx + dy * dy;
                float d = sqrtf(fmaxf(d2, 1e-12f));
                hit = (d <= 10.0f);
            }
            unsigned long long mk = __ballot(hit);
            int off = __popcll(mk & below);
            if (hit && mc + off < MAXC) { cd2[mc + off] = d2; cjj[mc + off] = p; }
            mc += (int)__popcll(mk);
        }
    }
    wsync();
    const int M = min(mc, MAXC);

    float thr_d2, thr_w;
    if (M > 32) {
        for (int k = lane; k < M; k += 64)
            atomicAdd(&hist[min(255, (int)(cd2[k] * BUCKSC))], 1);
        wsync();
        int4 h4 = *(const int4*)&hist[lane * 4];
        int hh0 = h4.x, hh1 = h4.y, hh2 = h4.z, hh3 = h4.w;
        int tot = hh0 + hh1 + hh2 + hh3;
        int sc = tot;
        #pragma unroll
        for (int o = 1; o < 64; o <<= 1) {
            int v = __shfl_up(sc, o);
            if (lane >= o) sc += v;
        }
        int ce = sc - tot;
        int fb = -1, fce = 0;
        if (ce <= 31 && 31 < ce + hh0) { fb = lane * 4 + 0; fce = ce; } ce += hh0;
        if (fb < 0 && ce <= 31 && 31 < ce + hh1) { fb = lane * 4 + 1; fce = ce; } ce += hh1;
        if (fb < 0 && ce <= 31 && 31 < ce + hh2) { fb = lane * 4 + 2; fce = ce; } ce += hh2;
        if (fb < 0 && ce <= 31 && 31 < ce + hh3) { fb = lane * 4 + 3; fce = ce; }
        unsigned long long mk1 = __ballot(fb >= 0);
        int src1 = (mk1 != 0ull) ? (__ffsll((unsigned long long)mk1) - 1) : 0;
        const int bstar   = __shfl(fb,  src1);
        const int cumexcl = __shfl(fce, src1);
        int bn = 0;
        for (int k0 = 0; k0 < M; k0 += 64) {
            const int k = k0 + lane;
            bool inb = (k < M) && (min(255, (int)(cd2[k] * BUCKSC)) == bstar);
            unsigned long long mk = __ballot(inb);
            int off = __popcll(mk & below);
            if (inb && bn + off < 32) blist[bn + off] = cd2[k];
            bn += (int)__popcll(mk);
        }
        wsync();
        bn = min(bn, 32);
        float mine = 0.0f; int ok = 0;
        if (lane < bn) {
            mine = blist[lane];
            int cl = 0, ceq = 0;
            for (int m = 0; m < bn; ++m) {
                cl  += (blist[m] <  mine);
                ceq += (blist[m] == mine);
            }
            int r = cumexcl + cl;
            ok = (r <= 31 && 31 < r + ceq);
        }
        unsigned long long mk2 = __ballot(ok);
        int src2 = (mk2 != 0ull) ? (__ffsll((unsigned long long)mk2) - 1) : 0;
        thr_d2 = __shfl(mine, src2);
        thr_w  = expf(-(thr_d2 / 50.0f));
    } else {
        thr_d2 = 3.4e38f;
        thr_w  = 0.0f;
    }

    const float marg = thr_d2 + 1e-4f;
    int kc = 0;
    for (int k0 = 0; k0 < M; k0 += 64) {
        const int k = k0 + lane;
        bool keep = false; float w = 0.0f; int jj = 0;
        if (k < M && cd2[k] <= marg) {
            w = expf(-(cd2[k] / 50.0f));
            if (w >= thr_w) { keep = true; jj = bIdx[cjj[k]]; }
        }
        unsigned long long mk = __ballot(keep);
        int off = __popcll(mk & below);
        if (keep && kc + off < MAXK)
            kwj[kc + off] = make_float2(w, __int_as_float(jj));
        kc += (int)__popcll(mk);
    }
    wsync();
    const int K = min(kc, MAXK);

    float2 pr = make_float2(0.0f, 0.0f);
    if (lane < K) pr = kwj[lane];
    float v = pr.x;
    #pragma unroll
    for (int o = 32; o > 0; o >>= 1) v += __shfl_xor(v, o);
    const float ssum = fmaxf(v, 1e-8f);
    const float wn = pr.x / ssum;
    const int   jn = __float_as_int(pr.y);
    const int   wi = __float_as_int(wn);

    const size_t NL = (size_t)N * 64;
    const float* F0 = F + lane;
    float* O0 = out + (size_t)i * 64 + lane;
    for (int b = 0; b < B; ++b) {
        float a = 0.0f;
        const float* Fb = F0 + (size_t)b * NL;
        for (int k = 0; k < K; ++k) {
            const float w = __int_as_float(__builtin_amdgcn_readlane(wi, k));
            const size_t o = (size_t)__builtin_amdgcn_readlane(jn, k) * 64;
            a += w * Fb[o];
        }
        O0[(size_t)b * NL] = a;
    }
}

extern "C" void kernel_launch(void* const* d_in, const int* in_sizes, int n_in,
                              void* d_out, int out_size, void* d_ws, size_t ws_size,
                              hipStream_t stream)
{
    const float* F = (const float*)d_in[0];   // features [B,N,64] f32
    const float* C = (const float*)d_in[1];   // coordinates [N,2] f32
    float* out = (float*)d_out;               // [B,N,64] f32

    const int N = in_sizes[1] / 2;            // 8192
    const int B = in_sizes[0] / (N * 64);     // 8

    // d_ws layout: cellStart | bXY | bIdx | kn | kv | (256-aligned) FB2
    char* ws = (char*)d_ws;
    int*    cellStart = (int*)(ws + 0);                        // 512 B
    float2* bXY       = (float2*)(ws + 512);                   // N*8
    int*    bIdx      = (int*)(ws + 512 + (size_t)N * 8);      // N*4
    size_t  off       = 512 + (size_t)N * 8 + (size_t)N * 4;
    off = (off + 15) & ~(size_t)15;
    int2*   kn        = (int2*)(ws + off);   off += (size_t)N * 8;
    float2* kv        = (float2*)(ws + off); off += (size_t)N * MAXK * 8;
    off = (off + 255) & ~(size_t)255;
    float*  FB2       = (float*)(ws + off);
    const size_t needFast = off + (size_t)N * B * 64 * sizeof(float);

    k_prep<<<1, 1024, 0, stream>>>(C, cellStart, bXY, bIdx, N);

    if (N == 8192 && B == 8 && ws_size >= needFast) {
        k_permute<<<4096, 256, 0, stream>>>(F, bIdx, FB2);
        // ATTRIBUTION: 4 identical (idempotent) select launches; wall-clock
        // delta vs R10 isolates k_select's duration.
        k_select <<<2048, 256, 0, stream>>>(bXY, bIdx, cellStart, kv, kn, N);
        k_select <<<2048, 256, 0, stream>>>(bXY, bIdx, cellStart, kv, kn, N);
        k_select <<<2048, 256, 0, stream>>>(bXY, bIdx, cellStart, kv, kn, N);
        k_select <<<2048, 256, 0, stream>>>(bXY, bIdx, cellStart, kv, kn, N);
        k_pool   <<< 512, 256, 0, stream>>>(FB2, kv, kn, out);
    } else {
        social_pool_fused<<<(N + 3) / 4, 256, 0, stream>>>(
            F, bXY, bIdx, cellStart, out, N, B);
    }
}

// Round 12
// 59.898 us; speedup vs baseline: 1.9870x; 1.9870x over previous
//
#include <hip/hip_runtime.h>
#include <math.h>

// SocialPooling: B=8, N=8192, D=64.
// w_ij = exp(-d2/50) if sqrt(max(d2,1e-12)) <= 10 else 0;
// keep w >= (32nd largest w in row); normalize by clip(row_sum,1e-8);
// out[b,i,d] = sum_j w_ij * F[b,j,d].
//
// R12. Attribution (R11): select=16.4us, pool~40us at 2 blocks/CU (25% occ,
// latency-starved); R8's full-occ original-index gather ran at L3 BW (~17
// TB/s) because 16MB/XCD working set >> 4MB L2. Fix both:
//  - k_select absorbs the FB2 permute (own-row copy, hides under select
//    stalls; kills the 7us permute launch). Selection math bit-identical.
//  - k_pool: 4096 blocks x 4 waves, wave = 1 row x 4 batches (batch-split).
//    Full 32 waves/CU + per-XCD live window ~1.4MB < 4MB L2 => gather at
//    ~L2 bandwidth (512MB / 34.5TB/s ~ 15us) instead of L3.

constexpr int   NCELL  = 10;
constexpr int   NCELL2 = 100;
constexpr int   MAXC   = 416;   // candidates/row: lambda~257, std~16 (+10σ)
constexpr int   MAXK   = 64;    // kept: 32 + boundary ties
constexpr float BUCKSC = 2.56f; // d2 in [0,100] -> bucket 0..255 (monotone)
constexpr int   NXCD   = 8;

__device__ __forceinline__ int cell_x(float x) {
    int c = (int)(x * 0.09765625f);   // 1/10.24 exact in f32
    return min(max(c, 0), NCELL - 1);
}
__device__ __forceinline__ int cell_of(float2 c) {
    return cell_x(c.y) * NCELL + cell_x(c.x);
}

// wave-synchronous LDS handoff (LDS is wave-private: drain lgkmcnt only)
__device__ __forceinline__ void wsync() {
    __builtin_amdgcn_wave_barrier();
    asm volatile("s_waitcnt lgkmcnt(0)" ::: "memory");
    __builtin_amdgcn_wave_barrier();
}

// ---- fused prep: zero + count + parallel scan + scatter, one block ----
__global__ __launch_bounds__(1024)
void k_prep(const float* __restrict__ C, int* __restrict__ cellStart,
            float2* __restrict__ bXY, int* __restrict__ bIdx, int N)
{
    __shared__ int h[128];
    __shared__ int cur[NCELL2];
    const int t = threadIdx.x;
    if (t < 128) h[t] = 0;
    __syncthreads();
    const float2* C2 = (const float2*)C;
    for (int j = t; j < N; j += 1024) atomicAdd(&h[cell_of(C2[j])], 1);
    __syncthreads();
    #pragma unroll
    for (int o = 1; o < 128; o <<= 1) {
        int u = (t < 128 && t >= o) ? h[t - o] : 0;
        __syncthreads();
        if (t < 128) h[t] += u;
        __syncthreads();
    }
    if (t < NCELL2) {
        int s = (t == 0) ? 0 : h[t - 1];
        cur[t] = s; cellStart[t] = s;
        if (t == 0) cellStart[NCELL2] = h[NCELL2 - 1];
    }
    __syncthreads();
    for (int j = t; j < N; j += 1024) {
        float2 c = C2[j];
        int pos = atomicAdd(&cur[cell_of(c)], 1);
        bXY[pos] = c; bIdx[pos] = j;
    }
}

// ---- selection (passes 1-3 bit-identical to R9..R11) + kv/kn write
//      + fused own-row FB2 copy: FB2[q][b][d] = F[b][bIdx[q]][d] ----
__global__ __launch_bounds__(256, 8)
void k_select(const float* __restrict__ F,
              const float2* __restrict__ bXY,
              const int* __restrict__ bIdx,
              const int* __restrict__ cellStart,
              float2* __restrict__ kv,       // [N][MAXK] (w, bitcast p)
              int2* __restrict__ kn,         // [N] (Kpad, original i)
              float* __restrict__ FB2,       // [N][8][64] batch-interleaved
              int N)
{
    __shared__ float  s_cd2[4][MAXC];
    __shared__ int    s_cjj[4][MAXC];
    __shared__ __align__(16) int s_hist[4][256];
    __shared__ float  s_blist[4][32];
    __shared__ float2 s_kwj[4][MAXK];

    const int t = threadIdx.x, wid = t >> 6, lane = t & 63;
    float*  cd2   = s_cd2[wid];
    int*    cjj   = s_cjj[wid];
    int*    hist  = s_hist[wid];
    float*  blist = s_blist[wid];
    float2* kwj   = s_kwj[wid];

    *(int4*)&hist[lane * 4] = make_int4(0, 0, 0, 0);

    const int bid = blockIdx.x, nb = gridDim.x;
    const int sb = (nb % NXCD == 0) ? (bid % NXCD) * (nb / NXCD) + bid / NXCD : bid;
    const int q = sb * 4 + wid;
    if (q >= N) return;

    const float2 ci = bXY[q];
    const int    i  = bIdx[q];
    const int cx = cell_x(ci.x), cy = cell_x(ci.y);
    const unsigned long long below = (1ull << lane) - 1ull;

    // fused permute: issue own-row feature copy loads EARLY (hide under
    // selection); lane = (b = lane>>3, d8 = (lane&7)*8); 2KB per row.
    const int cb  = lane >> 3;
    const int cd8 = (lane & 7) * 8;
    const float* csrc = F + ((size_t)cb * N + (size_t)i) * 64 + cd8;
    const float4 cv0 = *(const float4*)csrc;
    const float4 cv1 = *(const float4*)(csrc + 4);

    // pass 1: scan 3x3 cells; ballot+popc compaction; store position p
    int mc = 0;
    for (int ry = max(cy - 1, 0); ry <= min(cy + 1, NCELL - 1); ++ry) {
        const int c0 = ry * NCELL + max(cx - 1, 0);
        const int c1 = ry * NCELL + min(cx + 1, NCELL - 1);
        const int s = cellStart[c0], e = cellStart[c1 + 1];
        for (int p0 = s; p0 < e; p0 += 64) {
            const int p = p0 + lane;
            bool hit = false; float d2 = 0.0f;
            if (p < e) {
                float2 cp = bXY[p];
                float dx = ci.x - cp.x, dy = ci.y - cp.y;
                d2 = dx * dx + dy * dy;
                float d = sqrtf(fmaxf(d2, 1e-12f));   // exact ref boundary
                hit = (d <= 10.0f);
            }
            unsigned long long mk = __ballot(hit);
            int off = __popcll(mk & below);
            if (hit && mc + off < MAXC) { cd2[mc + off] = d2; cjj[mc + off] = p; }
            mc += (int)__popcll(mk);
        }
    }
    wsync();
    const int M = min(mc, MAXC);

    // write the staged copy now (loads have long since landed)
    float* cdst = FB2 + (size_t)q * 512 + cb * 64 + cd8;
    *(float4*)cdst = cv0;
    *(float4*)(cdst + 4) = cv1;

    // pass 2: 32nd-smallest d2 via per-wave 256-bin histogram
    float thr_d2, thr_w;
    if (M > 32) {
        for (int k = lane; k < M; k += 64)
            atomicAdd(&hist[min(255, (int)(cd2[k] * BUCKSC))], 1);
        wsync();
        int4 h4 = *(const int4*)&hist[lane * 4];
        int hh0 = h4.x, hh1 = h4.y, hh2 = h4.z, hh3 = h4.w;
        int tot = hh0 + hh1 + hh2 + hh3;
        int sc = tot;
        #pragma unroll
        for (int o = 1; o < 64; o <<= 1) {
            int v = __shfl_up(sc, o);
            if (lane >= o) sc += v;
        }
        int ce = sc - tot;
        int fb = -1, fce = 0;
        if (ce <= 31 && 31 < ce + hh0) { fb = lane * 4 + 0; fce = ce; } ce += hh0;
        if (fb < 0 && ce <= 31 && 31 < ce + hh1) { fb = lane * 4 + 1; fce = ce; } ce += hh1;
        if (fb < 0 && ce <= 31 && 31 < ce + hh2) { fb = lane * 4 + 2; fce = ce; } ce += hh2;
        if (fb < 0 && ce <= 31 && 31 < ce + hh3) { fb = lane * 4 + 3; fce = ce; }
        unsigned long long mk1 = __ballot(fb >= 0);
        int src1 = (mk1 != 0ull) ? (__ffsll((unsigned long long)mk1) - 1) : 0;
        const int bstar   = __shfl(fb,  src1);
        const int cumexcl = __shfl(fce, src1);
        int bn = 0;
        for (int k0 = 0; k0 < M; k0 += 64) {
            const int k = k0 + lane;
            bool inb = (k < M) && (min(255, (int)(cd2[k] * BUCKSC)) == bstar);
            unsigned long long mk = __ballot(inb);
            int off = __popcll(mk & below);
            if (inb && bn + off < 32) blist[bn + off] = cd2[k];
            bn += (int)__popcll(mk);
        }
        wsync();
        bn = min(bn, 32);
        float mine = 0.0f; int ok = 0;
        if (lane < bn) {
            mine = blist[lane];
            int cl = 0, ceq = 0;
            for (int m = 0; m < bn; ++m) {
                cl  += (blist[m] <  mine);
                ceq += (blist[m] == mine);
            }
            int r = cumexcl + cl;
            ok = (r <= 31 && 31 < r + ceq);
        }
        unsigned long long mk2 = __ballot(ok);
        int src2 = (mk2 != 0ull) ? (__ffsll((unsigned long long)mk2) - 1) : 0;
        thr_d2 = __shfl(mine, src2);
        thr_w  = expf(-(thr_d2 / 50.0f));
    } else {
        thr_d2 = 3.4e38f;
        thr_w  = 0.0f;
    }

    // pass 3: keep w >= thr_w over d2-margin superset (tie-exact); store p
    const float marg = thr_d2 + 1e-4f;
    int kc = 0;
    for (int k0 = 0; k0 < M; k0 += 64) {
        const int k = k0 + lane;
        bool keep = false; float w = 0.0f; int jj = 0;
        if (k < M && cd2[k] <= marg) {
            w = expf(-(cd2[k] / 50.0f));
            if (w >= thr_w) { keep = true; jj = cjj[k]; }
        }
        unsigned long long mk = __ballot(keep);
        int off = __popcll(mk & below);
        if (keep && kc + off < MAXK)
            kwj[kc + off] = make_float2(w, __int_as_float(jj));
        kc += (int)__popcll(mk);
    }
    wsync();
    const int K = min(kc, MAXK);

    // normalize in registers; lane l holds pair l
    float2 pr = make_float2(0.0f, 0.0f);
    if (lane < K) pr = kwj[lane];
    float v = pr.x;
    #pragma unroll
    for (int o = 32; o > 0; o >>= 1) v += __shfl_xor(v, o);
    const float ssum = fmaxf(v, 1e-8f);
    const float wn = pr.x / ssum;

    kv[(size_t)q * MAXK + lane] =
        (lane < K) ? make_float2(wn, pr.y) : make_float2(0.0f, __int_as_float(0));
    if (lane == 0) kn[q] = make_int2((K + 3) & ~3, i);
}

// ---- pooling: full-occupancy, batch-split, XCD-windowed ----
// 4096 blocks x 4 waves; wave = 1 row x 4 batches. half = bid>>11 (batches
// half*4..half*4+3) so the first 2048 in-flight blocks share batch-half 0:
// per-XCD live window = 1024 consecutive binned rows' neighborhoods x 1KB
// ~ 1.4MB < 4MB L2. lane = (b4 = lane>>4, dq = lane&15): per k-step the
// wave reads one contiguous 1KB burst of FB2 row p.
__global__ __launch_bounds__(256, 8)
void k_pool(const float* __restrict__ FB2,
            const float2* __restrict__ kv,
            const int2* __restrict__ kn,
            float* __restrict__ out)
{
    const int wid = threadIdx.x >> 6, lane = threadIdx.x & 63;
    const int half = blockIdx.x >> 11;            // batch half
    const int r    = blockIdx.x & 2047;
    const int xcd  = r & 7;
    const int slot = r >> 3;                      // [0,256)
    const int row  = xcd * 1024 + slot * 4 + wid; // consecutive binned rows
    const int b    = half * 4 + (lane >> 4);
    const int dq   = (lane & 15) * 4;
    const size_t NL = (size_t)8192 * 64;

    const int2 kni = kn[row];
    const int Kp = kni.x;                         // padded to x4; pad w = 0
    const int i  = kni.y;                         // original row index
    const float2 prl = kv[(size_t)row * MAXK + lane];
    const int wi = __float_as_int(prl.x);
    const int pi = __float_as_int(prl.y);

    float4 a = make_float4(0.f, 0.f, 0.f, 0.f);
    for (int k = 0; k < Kp; k += 4) {
        #pragma unroll
        for (int u = 0; u < 4; ++u) {
            const float w = __int_as_float(__builtin_amdgcn_readlane(wi, k + u));
            const int   p = __builtin_amdgcn_readlane(pi, k + u);
            const float4 f = *(const float4*)(FB2 + (size_t)p * 512 + b * 64 + dq);
            a.x += w * f.x; a.y += w * f.y; a.z += w * f.z; a.w += w * f.w;
        }
    }
    *(float4*)(out + (size_t)b * NL + (size_t)i * 64 + dq) = a;
}

// ---- generic fallback (R9's fused kernel, original-F gather) ----
__global__ __launch_bounds__(256, 8)
void social_pool_fused(const float* __restrict__ F,
                       const float2* __restrict__ bXY,
                       const int* __restrict__ bIdx,
                       const int* __restrict__ cellStart,
                       float* __restrict__ out, int N, int B)
{
    __shared__ float  s_cd2[4][MAXC];
    __shared__ int    s_cjj[4][MAXC];
    __shared__ __align__(16) int s_hist[4][256];
    __shared__ float  s_blist[4][32];
    __shared__ float2 s_kwj[4][MAXK];

    const int t = threadIdx.x, wid = t >> 6, lane = t & 63;
    float*  cd2   = s_cd2[wid];
    int*    cjj   = s_cjj[wid];
    int*    hist  = s_hist[wid];
    float*  blist = s_blist[wid];
    float2* kwj   = s_kwj[wid];

    *(int4*)&hist[lane * 4] = make_int4(0, 0, 0, 0);

    const int bid = blockIdx.x, nb = gridDim.x;
    const int sb = (nb % NXCD == 0) ? (bid % NXCD) * (nb / NXCD) + bid / NXCD : bid;
    const int q = sb * 4 + wid;
    if (q >= N) return;

    const float2 ci = bXY[q];
    const int    i  = bIdx[q];
    const int cx = cell_x(ci.x), cy = cell_x(ci.y);
    const unsigned long long below = (1ull << lane) - 1ull;

    int mc = 0;
    for (int ry = max(cy - 1, 0); ry <= min(cy + 1, NCELL - 1); ++ry) {
        const int c0 = ry * NCELL + max(cx - 1, 0);
        const int c1 = ry * NCELL + min(cx + 1, NCELL - 1);
        const int s = cellStart[c0], e = cellStart[c1 + 1];
        for (int p0 = s; p0 < e; p0 += 64) {
            const int p = p0 + lane;
            bool hit = false; float d2 = 0.0f;
            if (p < e) {
                float2 cp = bXY[p];
                float dx = ci.x - cp.x, dy = ci.y - cp.y;
                d2 = dx * dx + dy * dy;
                float d = sqrtf(fmaxf(d2, 1e-12f));
                hit = (d <= 10.0f);
            }
            unsigned long long mk = __ballot(hit);
            int off = __popcll(mk & below);
            if (hit && mc + off < MAXC) { cd2[mc + off] = d2; cjj[mc + off] = p; }
            mc += (int)__popcll(mk);
        }
    }
    wsync();
    const int M = min(mc, MAXC);

    float thr_d2, thr_w;
    if (M > 32) {
        for (int k = lane; k < M; k += 64)
            atomicAdd(&hist[min(255, (int)(cd2[k] * BUCKSC))], 1);
        wsync();
        int4 h4 = *(const int4*)&hist[lane * 4];
        int hh0 = h4.x, hh1 = h4.y, hh2 = h4.z, hh3 = h4.w;
        int tot = hh0 + hh1 + hh2 + hh3;
        int sc = tot;
        #pragma unroll
        for (int o = 1; o < 64; o <<= 1) {
            int v = __shfl_up(sc, o);
            if (lane >= o) sc += v;
        }
        int ce = sc - tot;
        int fb = -1, fce = 0;
        if (ce <= 31 && 31 < ce + hh0) { fb = lane * 4 + 0; fce = ce; } ce += hh0;
        if (fb < 0 && ce <= 31 && 31 < ce + hh1) { fb = lane * 4 + 1; fce = ce; } ce += hh1;
        if (fb < 0 && ce <= 31 && 31 < ce + hh2) { fb = lane * 4 + 2; fce = ce; } ce += hh2;
        if (fb < 0 && ce <= 31 && 31 < ce + hh3) { fb = lane * 4 + 3; fce = ce; }
        unsigned long long mk1 = __ballot(fb >= 0);
        int src1 = (mk1 != 0ull) ? (__ffsll((unsigned long long)mk1) - 1) : 0;
        const int bstar   = __shfl(fb,  src1);
        const int cumexcl = __shfl(fce, src1);
        int bn = 0;
        for (int k0 = 0; k0 < M; k0 += 64) {
            const int k = k0 + lane;
            bool inb = (k < M) && (min(255, (int)(cd2[k] * BUCKSC)) == bstar);
            unsigned long long mk = __ballot(inb);
            int off = __popcll(mk & below);
            if (inb && bn + off < 32) blist[bn + off] = cd2[k];
            bn += (int)__popcll(mk);
        }
        wsync();
        bn = min(bn, 32);
        float mine = 0.0f; int ok = 0;
        if (lane < bn) {
            mine = blist[lane];
            int cl = 0, ceq = 0;
            for (int m = 0; m < bn; ++m) {
                cl  += (blist[m] <  mine);
                ceq += (blist[m] == mine);
            }
            int r = cumexcl + cl;
            ok = (r <= 31 && 31 < r + ceq);
        }
        unsigned long long mk2 = __ballot(ok);
        int src2 = (mk2 != 0ull) ? (__ffsll((unsigned long long)mk2) - 1) : 0;
        thr_d2 = __shfl(mine, src2);
        thr_w  = expf(-(thr_d2 / 50.0f));
    } else {
        thr_d2 = 3.4e38f;
        thr_w  = 0.0f;
    }

    const float marg = thr_d2 + 1e-4f;
    int kc = 0;
    for (int k0 = 0; k0 < M; k0 += 64) {
        const int k = k0 + lane;
        bool keep = false; float w = 0.0f; int jj = 0;
        if (k < M && cd2[k] <= marg) {
            w = expf(-(cd2[k] / 50.0f));
            if (w >= thr_w) { keep = true; jj = bIdx[cjj[k]]; }
        }
        unsigned long long mk = __ballot(keep);
        int off = __popcll(mk & below);
        if (keep && kc + off < MAXK)
            kwj[kc + off] = make_float2(w, __int_as_float(jj));
        kc += (int)__popcll(mk);
    }
    wsync();
    const int K = min(kc, MAXK);

    float2 pr = make_float2(0.0f, 0.0f);
    if (lane < K) pr = kwj[lane];
    float v = pr.x;
    #pragma unroll
    for (int o = 32; o > 0; o >>= 1) v += __shfl_xor(v, o);
    const float ssum = fmaxf(v, 1e-8f);
    const float wn = pr.x / ssum;
    const int   jn = __float_as_int(pr.y);
    const int   wi = __float_as_int(wn);

    const size_t NL = (size_t)N * 64;
    const float* F0 = F + lane;
    float* O0 = out + (size_t)i * 64 + lane;
    for (int b = 0; b < B; ++b) {
        float a = 0.0f;
        const float* Fb = F0 + (size_t)b * NL;
        for (int k = 0; k < K; ++k) {
            const float w = __int_as_float(__builtin_amdgcn_readlane(wi, k));
            const size_t o = (size_t)__builtin_amdgcn_readlane(jn, k) * 64;
            a += w * Fb[o];
        }
        O0[(size_t)b * NL] = a;
    }
}

extern "C" void kernel_launch(void* const* d_in, const int* in_sizes, int n_in,
                              void* d_out, int out_size, void* d_ws, size_t ws_size,
                              hipStream_t stream)
{
    const float* F = (const float*)d_in[0];   // features [B,N,64] f32
    const float* C = (const float*)d_in[1];   // coordinates [N,2] f32
    float* out = (float*)d_out;               // [B,N,64] f32

    const int N = in_sizes[1] / 2;            // 8192
    const int B = in_sizes[0] / (N * 64);     // 8

    // d_ws layout: cellStart | bXY | bIdx | kn | kv | (256-aligned) FB2
    char* ws = (char*)d_ws;
    int*    cellStart = (int*)(ws + 0);                        // 512 B
    float2* bXY       = (float2*)(ws + 512);                   // N*8
    int*    bIdx      = (int*)(ws + 512 + (size_t)N * 8);      // N*4
    size_t  off       = 512 + (size_t)N * 8 + (size_t)N * 4;
    off = (off + 15) & ~(size_t)15;
    int2*   kn        = (int2*)(ws + off);   off += (size_t)N * 8;
    float2* kv        = (float2*)(ws + off); off += (size_t)N * MAXK * 8;
    off = (off + 255) & ~(size_t)255;
    float*  FB2       = (float*)(ws + off);
    const size_t needFast = off + (size_t)N * B * 64 * sizeof(float);

    k_prep<<<1, 1024, 0, stream>>>(C, cellStart, bXY, bIdx, N);

    if (N == 8192 && B == 8 && ws_size >= needFast) {
        k_select<<<2048, 256, 0, stream>>>(F, bXY, bIdx, cellStart, kv, kn, FB2, N);
        k_pool  <<<4096, 256, 0, stream>>>(FB2, kv, kn, out);
    } else {
        social_pool_fused<<<(N + 3) / 4, 256, 0, stream>>>(
            F, bXY, bIdx, cellStart, out, N, B);
    }
}